// Round 1
// baseline (144.725 us; speedup 1.0000x reference)
//
#include <hip/hip_runtime.h>
#include <hip/hip_bf16.h>

// GATLayer with scalar attention: softmax over constant rows => uniform 1/deg
// over DISTINCT neighbors. Aggregation commutes with the linear transform:
//   out[n, h*D+d] = sum_k W[h,d,k] * agg_x[n,k]
//   agg_x[n,:]    = mean_{j in distinct nbr(n)} x[j,:]   (or mean over all N if deg==0)

constexpr int NN = 4096;          // nodes
constexpr int DD = 256;           // channels
constexpr int HH = 8;             // heads
constexpr int EE = 131072;        // edges
constexpr int MW = NN / 32;       // 128 mask words per row
constexpr int NOUT = HH * DD;     // 2048

// ---------------- edge scatter: dedupe via bitmask ----------------
__global__ void scatter_edges_k(const int* __restrict__ ei, int stride,
                                unsigned int* __restrict__ mask) {
    int e = blockIdx.x * blockDim.x + threadIdx.x;
    if (e >= EE) return;
    int u = ei[(size_t)e * stride];              // src (row of adj)
    int v = ei[((size_t)EE + e) * stride];       // dst (col of adj)
    atomicOr(&mask[(size_t)u * MW + (v >> 5)], 1u << (v & 31));
}

// ---------------- column sums of x (only needed for deg==0 rows) ----------------
__global__ void colsum_k(const float* __restrict__ x, float* __restrict__ colsum) {
    int t = threadIdx.x;                 // column 0..255
    int r0 = blockIdx.x * 64;
    float acc = 0.f;
    for (int r = 0; r < 64; ++r) acc += x[(size_t)(r0 + r) * DD + t];
    atomicAdd(&colsum[t], acc);
}

// ---------------- per-node neighbor mean of x ----------------
__global__ __launch_bounds__(256) void aggregate_k(const float* __restrict__ x,
                            const unsigned int* __restrict__ mask,
                            const float* __restrict__ colsum,
                            float* __restrict__ agg) {
    int i = blockIdx.x;
    int t = threadIdx.x;                 // channel 0..255
    __shared__ unsigned int mrow[MW];
    if (t < MW) mrow[t] = mask[(size_t)i * MW + t];
    __syncthreads();

    int deg = 0;
    for (int w = 0; w < MW; ++w) deg += __popc(mrow[w]);

    float acc = 0.f;
    for (int w = 0; w < MW; ++w) {
        unsigned int m = mrow[w];
        while (m) {                      // uniform across block: no divergence
            int b = __ffs(m) - 1;
            m &= m - 1;
            acc += x[(size_t)(w * 32 + b) * DD + t];   // coalesced 1KB row read
        }
    }
    float res = (deg > 0) ? acc * (1.f / (float)deg)
                          : colsum[t] * (1.f / (float)NN);
    agg[(size_t)i * DD + t] = res;
}

// ---------------- fp32 GEMM: C[4096][2048] = A[4096][256] * B[2048][256]^T ----------------
constexpr int BM = 64, BN = 64, BK = 16;

__global__ __launch_bounds__(256) void gemm_k(const float* __restrict__ A,
                                              const float* __restrict__ B,
                                              float* __restrict__ C) {
    __shared__ float As[BK][BM + 4];   // +4 floats: stride 272B = 16B-aligned, conflict-free
    __shared__ float Bs[BK][BN + 4];
    int tid = threadIdx.x;
    int tx = tid & 15;                 // output col group
    int ty = tid >> 4;                 // output row group
    int lk = tid & 15;                 // load: k within tile
    int lm = tid >> 4;                 // load: row within tile (x4)
    int m0 = blockIdx.y * BM;
    int n0 = blockIdx.x * BN;

    float acc[4][4] = {};

    for (int k0 = 0; k0 < DD; k0 += BK) {
#pragma unroll
        for (int i = 0; i < 4; ++i) {
            As[lk][lm + 16 * i] = A[(size_t)(m0 + lm + 16 * i) * DD + k0 + lk];
            Bs[lk][lm + 16 * i] = B[(size_t)(n0 + lm + 16 * i) * DD + k0 + lk];
        }
        __syncthreads();
#pragma unroll
        for (int k = 0; k < BK; ++k) {
            float a[4], b[4];
#pragma unroll
            for (int i = 0; i < 4; ++i) a[i] = As[k][ty * 4 + i];
#pragma unroll
            for (int j = 0; j < 4; ++j) b[j] = Bs[k][tx * 4 + j];
#pragma unroll
            for (int i = 0; i < 4; ++i)
#pragma unroll
                for (int j = 0; j < 4; ++j)
                    acc[i][j] += a[i] * b[j];
        }
        __syncthreads();
    }

#pragma unroll
    for (int i = 0; i < 4; ++i) {
        int m = m0 + ty * 4 + i;
        float4 v = make_float4(acc[i][0], acc[i][1], acc[i][2], acc[i][3]);
        *reinterpret_cast<float4*>(&C[(size_t)m * NOUT + n0 + tx * 4]) = v;
    }
}

extern "C" void kernel_launch(void* const* d_in, const int* in_sizes, int n_in,
                              void* d_out, int out_size, void* d_ws, size_t ws_size,
                              hipStream_t stream) {
    const float* x  = (const float*)d_in[0];
    const float* lw = (const float*)d_in[1];   // [H][D][D] == [2048][256] row-major
    const int*   ei = (const int*)d_in[4];
    float* out = (float*)d_out;

    char* ws = (char*)d_ws;
    float*        agg    = (float*)ws;                                   // 4 MB
    unsigned int* mask   = (unsigned int*)(ws + (size_t)NN * DD * 4);    // 2 MB
    float*        colsum = (float*)(ws + (size_t)NN * DD * 4
                                       + (size_t)NN * MW * 4);           // 1 KB

    // int64 edge_index delivered as int32? (2*E elements) vs raw int64 (low words, stride 2)
    int stride = (in_sizes[4] == 2 * EE) ? 1 : 2;

    // zero mask + colsum (contiguous) every call: ws is poisoned, atomics accumulate
    hipMemsetAsync(mask, 0, (size_t)NN * MW * 4 + (size_t)DD * 4, stream);

    scatter_edges_k<<<EE / 256, 256, 0, stream>>>(ei, stride, mask);
    colsum_k<<<NN / 64, 256, 0, stream>>>(x, colsum);
    aggregate_k<<<NN, 256, 0, stream>>>(x, mask, colsum, agg);

    dim3 ggrid(NOUT / BN, NN / BM);   // (32, 64)
    gemm_k<<<ggrid, 256, 0, stream>>>(agg, lw, out);
}

// Round 2
// 60.086 us; speedup vs baseline: 2.4086x; 2.4086x over previous
//
#include <hip/hip_runtime.h>
#include <hip/hip_bf16.h>

// GATLayer with scalar attention => uniform 1/deg over DISTINCT neighbors.
//   out[n, h*D+d] = sum_k W[h,d,k] * agg_x[n,k]
//   agg_x[n,:]    = mean_{j in distinct nbr(n)} x[j,:]  (mean over all N if deg==0)
// agg + W cast to bf16, final GEMM via MFMA.

constexpr int NN = 4096;          // nodes
constexpr int DD = 256;           // channels
constexpr int HH = 8;             // heads
constexpr int EE = 131072;        // edges
constexpr int MW = NN / 32;       // 128 mask words per row
constexpr int NOUT = HH * DD;     // 2048

typedef __attribute__((ext_vector_type(4))) float f32x4;
typedef __attribute__((ext_vector_type(8))) short s16x8;

__device__ inline short f2bf(float f) {
    __hip_bfloat16 h = __float2bfloat16(f);
    return *reinterpret_cast<short*>(&h);
}

// ---------------- edge scatter: dedupe via bitmask ----------------
__global__ void scatter_edges_k(const int* __restrict__ ei, int stride,
                                unsigned int* __restrict__ mask) {
    int e = blockIdx.x * blockDim.x + threadIdx.x;
    if (e >= EE) return;
    int u = ei[(size_t)e * stride];              // src (row of adj)
    int v = ei[((size_t)EE + e) * stride];       // dst (col of adj)
    atomicOr(&mask[(size_t)u * MW + (v >> 5)], 1u << (v & 31));
}

// ---------------- column sums of x (only needed for deg==0 rows) ----------------
__global__ void colsum_k(const float* __restrict__ x, float* __restrict__ colsum) {
    int t = threadIdx.x;                 // column 0..255
    int r0 = blockIdx.x * 64;
    float acc = 0.f;
    for (int r = 0; r < 64; ++r) acc += x[(size_t)(r0 + r) * DD + t];
    atomicAdd(&colsum[t], acc);
}

// ---------------- W fp32 -> bf16 ----------------
__global__ void cvt_w_k(const float* __restrict__ w, short* __restrict__ wb) {
    int i = blockIdx.x * blockDim.x + threadIdx.x;   // one float4 per thread
    float4 v = reinterpret_cast<const float4*>(w)[i];
    short4 o;
    o.x = f2bf(v.x); o.y = f2bf(v.y); o.z = f2bf(v.z); o.w = f2bf(v.w);
    reinterpret_cast<short4*>(wb)[i] = o;
}

// ---------------- per-node neighbor mean of x (wave-split + float4) ----------------
__global__ __launch_bounds__(256) void aggregate_k(
        const float* __restrict__ x, const unsigned int* __restrict__ mask,
        const float* __restrict__ colsum, short* __restrict__ aggb) {
    int i = blockIdx.x;
    int t = threadIdx.x;
    int slot = t >> 6;            // wave id 0..3: owns words slot, slot+4, ...
    int c4 = (t & 63) << 2;       // 4 channels per lane -> 64 lanes = full row
    __shared__ unsigned int mrow[MW];
    __shared__ float part[4][DD];
    __shared__ int degs[4];
    if (t < MW) mrow[t] = mask[(size_t)i * MW + t];
    __syncthreads();

    float4 acc = make_float4(0.f, 0.f, 0.f, 0.f);
    int dp = 0;
    for (int w = slot; w < MW; w += 4) {
        unsigned int m = mrow[w];
        dp += __popc(m);
        while (m) {                      // wave-uniform: no divergence
            int b = __ffs(m) - 1;
            m &= m - 1;
            const float4 v = *reinterpret_cast<const float4*>(
                &x[(size_t)(w * 32 + b) * DD + c4]);   // 1KB/row per wave
            acc.x += v.x; acc.y += v.y; acc.z += v.z; acc.w += v.w;
        }
    }
    *reinterpret_cast<float4*>(&part[slot][c4]) = acc;
    if ((t & 63) == 0) degs[slot] = dp;
    __syncthreads();

    int deg = degs[0] + degs[1] + degs[2] + degs[3];
    float s = part[0][t] + part[1][t] + part[2][t] + part[3][t];
    float res = (deg > 0) ? s * (1.f / (float)deg)
                          : colsum[t] * (1.f / (float)NN);
    aggb[(size_t)i * DD + t] = f2bf(res);
}

// ------------- MFMA GEMM: C[4096][2048] = A[4096][256] * B[2048][256]^T -------------
// bf16 inputs, fp32 out. 128x128 block tile, 4 waves (2x2), 64x64 per wave.
// K=256 => 8 steps of 32; fragments loaded direct from global (A/B are L2-resident).
__global__ __launch_bounds__(256) void gemm_mfma_k(
        const short* __restrict__ A, const short* __restrict__ B,
        float* __restrict__ C) {
    int tid = threadIdx.x;
    int lane = tid & 63;
    int w = tid >> 6;
    int wr = w >> 1, wc = w & 1;
    int m0 = blockIdx.y * 128 + wr * 64;
    int n0 = blockIdx.x * 128 + wc * 64;
    int lr = lane & 15;                  // row (A) / col (B) within fragment
    int lk = (lane >> 4) * 8;            // k sub-block within 32-step

    f32x4 acc[4][4] = {};

    for (int k0 = 0; k0 < DD; k0 += 32) {
        s16x8 a[4], b[4];
#pragma unroll
        for (int i = 0; i < 4; ++i)
            a[i] = *reinterpret_cast<const s16x8*>(
                &A[(size_t)(m0 + i * 16 + lr) * DD + k0 + lk]);
#pragma unroll
        for (int j = 0; j < 4; ++j)
            b[j] = *reinterpret_cast<const s16x8*>(
                &B[(size_t)(n0 + j * 16 + lr) * DD + k0 + lk]);
#pragma unroll
        for (int i = 0; i < 4; ++i)
#pragma unroll
            for (int j = 0; j < 4; ++j)
                acc[i][j] = __builtin_amdgcn_mfma_f32_16x16x32_bf16(
                    a[i], b[j], acc[i][j], 0, 0, 0);
    }

    // C/D layout: col = lane&15, row = (lane>>4)*4 + reg
    int crow = (lane >> 4) * 4;
    int ccol = lane & 15;
#pragma unroll
    for (int i = 0; i < 4; ++i)
#pragma unroll
        for (int j = 0; j < 4; ++j)
#pragma unroll
            for (int r = 0; r < 4; ++r)
                C[(size_t)(m0 + i * 16 + crow + r) * NOUT + n0 + j * 16 + ccol]
                    = acc[i][j][r];
}

extern "C" void kernel_launch(void* const* d_in, const int* in_sizes, int n_in,
                              void* d_out, int out_size, void* d_ws, size_t ws_size,
                              hipStream_t stream) {
    const float* x  = (const float*)d_in[0];
    const float* lw = (const float*)d_in[1];   // [H][D][D] == [2048][256] row-major
    const int*   ei = (const int*)d_in[4];
    float* out = (float*)d_out;

    char* ws = (char*)d_ws;
    unsigned int* mask   = (unsigned int*)ws;                             // 2 MB
    float*        colsum = (float*)(ws + (size_t)NN * MW * 4);            // 1 KB
    short*        aggb   = (short*)(ws + (size_t)NN * MW * 4 + 4096);     // 2 MB bf16
    short*        lwb    = (short*)(ws + (size_t)NN * MW * 4 + 4096
                                       + (size_t)NN * DD * 2);            // 1 MB bf16

    // int64 edge_index delivered as int32 (2E elements) vs raw int64 (low words)
    int stride = (in_sizes[4] == 2 * EE) ? 1 : 2;

    hipMemsetAsync(mask, 0, (size_t)NN * MW * 4 + (size_t)DD * 4, stream);

    scatter_edges_k<<<EE / 256, 256, 0, stream>>>(ei, stride, mask);
    cvt_w_k<<<(NOUT * DD / 4) / 256, 256, 0, stream>>>(lw, lwb);
    colsum_k<<<NN / 64, 256, 0, stream>>>(x, colsum);
    aggregate_k<<<NN, 256, 0, stream>>>(x, mask, colsum, aggb);

    dim3 ggrid(NOUT / 128, NN / 128);   // (16, 32)
    gemm_mfma_k<<<ggrid, 256, 0, stream>>>(aggb, lwb, out);
}

// Round 3
// 56.135 us; speedup vs baseline: 2.5782x; 1.0704x over previous
//
#include <hip/hip_runtime.h>
#include <hip/hip_bf16.h>

// GATLayer with scalar attention => uniform 1/deg over DISTINCT neighbors.
//   out[n, h*D+d] = sum_k W[h,d,k] * agg_x[n,k]
//   agg_x[n,:]    = mean_{j in distinct nbr(n)} x[j,:]  (mean over all N if deg==0)
// agg + W cast to bf16, final GEMM via MFMA. 4 launches total.

constexpr int NN = 4096;          // nodes
constexpr int DD = 256;           // channels
constexpr int HH = 8;             // heads
constexpr int EE = 131072;        // edges
constexpr int MW = NN / 32;       // 128 mask words per row
constexpr int NOUT = HH * DD;     // 2048
constexpr int ZERO_F4 = (NN * MW * 4 + DD * 4) / 16;   // mask + colsum, float4 units

typedef __attribute__((ext_vector_type(4))) float f32x4;
typedef __attribute__((ext_vector_type(8))) short s16x8;

__device__ inline short f2bf(float f) {
    __hip_bfloat16 h = __float2bfloat16(f);
    return *reinterpret_cast<short*>(&h);
}

// ---- stage 1 (fused): zero mask+colsum via float4 stores; convert W to bf16 ----
__global__ __launch_bounds__(256) void prep_k(const float* __restrict__ w,
                                              short* __restrict__ wb,
                                              float4* __restrict__ zbase) {
    int b = blockIdx.x;
    int t = threadIdx.x;
    if (b < 513) {                       // zero 2 MB mask + 1 KB colsum
        int idx = b * 256 + t;
        if (idx < ZERO_F4) zbase[idx] = make_float4(0.f, 0.f, 0.f, 0.f);
    } else {                             // W fp32 -> bf16, one float4 per thread
        int i = (b - 513) * 256 + t;     // 0 .. 131071
        float4 v = reinterpret_cast<const float4*>(w)[i];
        short4 o;
        o.x = f2bf(v.x); o.y = f2bf(v.y); o.z = f2bf(v.z); o.w = f2bf(v.w);
        reinterpret_cast<short4*>(wb)[i] = o;
    }
}

// ---- stage 2 (fused): edge scatter into bitmask; colsum of x (deg==0 fallback) ----
__global__ __launch_bounds__(256) void edges_colsum_k(
        const int* __restrict__ ei, int stride, unsigned int* __restrict__ mask,
        const float* __restrict__ x, float* __restrict__ colsum) {
    int b = blockIdx.x;
    int t = threadIdx.x;
    if (b < 512) {                       // 512*256 = 131072 edges
        int e = b * 256 + t;
        int u = ei[(size_t)e * stride];              // src (row of adj)
        int v = ei[((size_t)EE + e) * stride];       // dst (col of adj)
        atomicOr(&mask[(size_t)u * MW + (v >> 5)], 1u << (v & 31));
    } else {                             // 64 blocks x 64 rows
        int r0 = (b - 512) * 64;
        float acc = 0.f;
        for (int r = 0; r < 64; ++r) acc += x[(size_t)(r0 + r) * DD + t];
        atomicAdd(&colsum[t], acc);
    }
}

// ---- stage 3: per-node neighbor mean of x (wave-split words + float4 lanes) ----
__global__ __launch_bounds__(256) void aggregate_k(
        const float* __restrict__ x, const unsigned int* __restrict__ mask,
        const float* __restrict__ colsum, short* __restrict__ aggb) {
    int i = blockIdx.x;
    int t = threadIdx.x;
    int slot = t >> 6;            // wave id 0..3: owns words slot, slot+4, ...
    int c4 = (t & 63) << 2;       // 4 channels per lane -> 64 lanes = full row
    __shared__ unsigned int mrow[MW];
    __shared__ float part[4][DD];
    __shared__ int degs[4];
    if (t < MW) mrow[t] = mask[(size_t)i * MW + t];
    __syncthreads();

    float4 acc = make_float4(0.f, 0.f, 0.f, 0.f);
    int dp = 0;
    for (int w = slot; w < MW; w += 4) {
        unsigned int m = mrow[w];
        dp += __popc(m);
        while (m) {                      // wave-uniform: no divergence
            int b = __ffs(m) - 1;
            m &= m - 1;
            const float4 v = *reinterpret_cast<const float4*>(
                &x[(size_t)(w * 32 + b) * DD + c4]);   // 1KB/row per wave
            acc.x += v.x; acc.y += v.y; acc.z += v.z; acc.w += v.w;
        }
    }
    *reinterpret_cast<float4*>(&part[slot][c4]) = acc;
    if ((t & 63) == 0) degs[slot] = dp;
    __syncthreads();

    int deg = degs[0] + degs[1] + degs[2] + degs[3];
    float s = part[0][t] + part[1][t] + part[2][t] + part[3][t];
    float res = (deg > 0) ? s * (1.f / (float)deg)
                          : colsum[t] * (1.f / (float)NN);
    aggb[(size_t)i * DD + t] = f2bf(res);
}

// ------- stage 4: MFMA GEMM  C[4096][2048] = A[4096][256] * B[2048][256]^T -------
// bf16 in, fp32 out. 128x128 block tile, 4 waves (2x2), 64x64 per wave.
// K=256 => 8 steps of 32; fragments direct from global (A/B L2-resident).
__global__ __launch_bounds__(256) void gemm_mfma_k(
        const short* __restrict__ A, const short* __restrict__ B,
        float* __restrict__ C) {
    int tid = threadIdx.x;
    int lane = tid & 63;
    int w = tid >> 6;
    int wr = w >> 1, wc = w & 1;
    int m0 = blockIdx.y * 128 + wr * 64;
    int n0 = blockIdx.x * 128 + wc * 64;
    int lr = lane & 15;                  // row (A) / col (B) within fragment
    int lk = (lane >> 4) * 8;            // k sub-block within 32-step

    f32x4 acc[4][4] = {};

    for (int k0 = 0; k0 < DD; k0 += 32) {
        s16x8 a[4], b[4];
#pragma unroll
        for (int i = 0; i < 4; ++i)
            a[i] = *reinterpret_cast<const s16x8*>(
                &A[(size_t)(m0 + i * 16 + lr) * DD + k0 + lk]);
#pragma unroll
        for (int j = 0; j < 4; ++j)
            b[j] = *reinterpret_cast<const s16x8*>(
                &B[(size_t)(n0 + j * 16 + lr) * DD + k0 + lk]);
#pragma unroll
        for (int i = 0; i < 4; ++i)
#pragma unroll
            for (int j = 0; j < 4; ++j)
                acc[i][j] = __builtin_amdgcn_mfma_f32_16x16x32_bf16(
                    a[i], b[j], acc[i][j], 0, 0, 0);
    }

    // C/D layout: col = lane&15, row = (lane>>4)*4 + reg
    int crow = (lane >> 4) * 4;
    int ccol = lane & 15;
#pragma unroll
    for (int i = 0; i < 4; ++i)
#pragma unroll
        for (int j = 0; j < 4; ++j)
#pragma unroll
            for (int r = 0; r < 4; ++r)
                C[(size_t)(m0 + i * 16 + crow + r) * NOUT + n0 + j * 16 + ccol]
                    = acc[i][j][r];
}

extern "C" void kernel_launch(void* const* d_in, const int* in_sizes, int n_in,
                              void* d_out, int out_size, void* d_ws, size_t ws_size,
                              hipStream_t stream) {
    const float* x  = (const float*)d_in[0];
    const float* lw = (const float*)d_in[1];   // [H][D][D] == [2048][256] row-major
    const int*   ei = (const int*)d_in[4];
    float* out = (float*)d_out;

    char* ws = (char*)d_ws;
    unsigned int* mask   = (unsigned int*)ws;                             // 2 MB
    float*        colsum = (float*)(ws + (size_t)NN * MW * 4);            // 1 KB
    short*        aggb   = (short*)(ws + (size_t)NN * MW * 4 + 1024);     // 2 MB bf16
    short*        lwb    = (short*)(ws + (size_t)NN * MW * 4 + 1024
                                       + (size_t)NN * DD * 2);            // 1 MB bf16

    // int64 edge_index delivered as int32 (2E elements) vs raw int64 (low words)
    int stride = (in_sizes[4] == 2 * EE) ? 1 : 2;

    prep_k<<<513 + 512, 256, 0, stream>>>(lw, lwb, (float4*)ws);
    edges_colsum_k<<<512 + 64, 256, 0, stream>>>(ei, stride, mask, x, colsum);
    aggregate_k<<<NN, 256, 0, stream>>>(x, mask, colsum, aggb);

    dim3 ggrid(NOUT / 128, NN / 128);   // (16, 32)
    gemm_mfma_k<<<ggrid, 256, 0, stream>>>(aggb, lwb, out);
}